// Round 11
// baseline (2247.575 us; speedup 1.0000x reference)
//
#include <hip/hip_runtime.h>
#include <stdint.h>

typedef __attribute__((ext_vector_type(8))) short s16x8;
typedef __attribute__((ext_vector_type(8))) unsigned short u16x8;
typedef __attribute__((ext_vector_type(4))) unsigned short u16x4;
typedef __attribute__((ext_vector_type(4))) float f32x4;

__device__ inline unsigned short f2b(float f){
  unsigned u = __builtin_bit_cast(unsigned, f);
  u = u + 0x7fffu + ((u >> 16) & 1u);
  return (unsigned short)(u >> 16);
}
__device__ inline float b2f(unsigned short h){
  unsigned u = ((unsigned)h) << 16;
  return __builtin_bit_cast(float, u);
}

typedef __attribute__((address_space(1))) const unsigned g_uint;
typedef __attribute__((address_space(3))) unsigned l_uint;

__device__ inline void gload_lds16(const void* g, void* l){
  __builtin_amdgcn_global_load_lds((g_uint*)reinterpret_cast<uintptr_t>(g),
                                   (l_uint*)reinterpret_cast<uintptr_t>(l), 16, 0, 0);
}

#define BARF() { __builtin_amdgcn_s_barrier(); asm volatile("" ::: "memory"); }

// plain bijective XCD swizzle (total % 8 == 0) — round-8 proven form
__device__ inline unsigned xcd_swizzle(unsigned lin, unsigned tot){
  const unsigned q = tot >> 3;
  return (lin & 7) * q + (lin >> 3);
}

// ============================================================================
// 256x256 8-phase GEMM (T2+T3+T4+T5), C = A·B^T, K multiple of 128.
// EPI 5: Cb = bf16(exp(v*scale)) + fused row-sum atomics into lsum
// EPI 6: EPI5 + Cf = v*scale
// EPI 7: o = Cf[idx] + v/lsum[row]; Cf = o; Cb = bf16(o)   (attention update)
// ============================================================================
template<int EPI>
__global__ __launch_bounds__(512, 2) void gemm256(
    const unsigned short* __restrict__ A, const unsigned short* __restrict__ B,
    int M, int N, int K, float scale,
    float* __restrict__ Cf, unsigned short* __restrict__ Cb,
    float* __restrict__ lsum)
{
  __shared__ __align__(16) char ldsraw[131072];
  const int tid  = threadIdx.x;
  const int wid  = tid >> 6, lane = tid & 63;
  const int wm   = wid >> 2, wn = wid & 3;

  const unsigned gx = gridDim.x, gy = gridDim.y;
  const unsigned lin = blockIdx.x + gx*blockIdx.y;
  const unsigned w   = xcd_swizzle(lin, gx*gy);
  const int bm = (w / gx) * 256, bn = (w % gx) * 256;

  const int NT = K >> 6;

  f32x4 acc[8][4] = {};

  auto stageA = [&](int T, int halfm){
    const int kb = T << 6;
    char* ldsb = ldsraw + ((T & 1) << 16) + halfm*16384;
    #pragma unroll
    for (int i = 0; i < 2; ++i){
      const int lr  = i*64 + (tid >> 3);
      const int gtr = halfm*64 + ((lr < 64) ? lr : lr + 64);
      const int sc  = ((tid & 7)*8) ^ ((lr & 7)*8);
      gload_lds16(A + (size_t)(bm + gtr)*K + kb + sc, ldsb + i*8192 + tid*16);
    }
  };
  auto stageB = [&](int T, int halfk){
    const int kb = (T << 6) + halfk*32;
    char* ldsb = ldsraw + ((T & 1) << 16) + 32768 + halfk*16384;
    #pragma unroll
    for (int i = 0; i < 2; ++i){
      const int lr = i*128 + (tid >> 2);
      const int sc = ((tid & 3)*8) ^ ((lr & 3)*8);
      gload_lds16(B + (size_t)(bn + lr)*K + kb + sc, ldsb + i*8192 + tid*16);
    }
  };

  const int fr = lane & 15;
  const int fo = (lane >> 4) << 4;
  const int amask = (fr & 7) << 4;
  const int bmask = (fr & 3) << 4;

  auto rdA = [&](const char* ldsS, int mh, int kk, s16x8* af){
    const char* ab = ldsS + mh*16384;
    #pragma unroll
    for (int mf = 0; mf < 4; ++mf){
      const int r = wm*64 + mf*16 + fr;
      af[mf] = *(const s16x8*)(ab + r*128 + ((kk*64 + fo) ^ amask));
    }
  };
  auto rdB = [&](const char* ldsS, int kk, s16x8* bf){
    const char* bb = ldsS + 32768 + kk*16384;
    #pragma unroll
    for (int nf = 0; nf < 4; ++nf){
      const int r = wn*64 + nf*16 + fr;
      bf[nf] = *(const s16x8*)(bb + r*64 + (fo ^ bmask));
    }
  };

  stageB(0, 0); stageA(0, 0); stageA(0, 1); stageB(0, 1);
  stageB(1, 0); stageA(1, 0);
  asm volatile("s_waitcnt vmcnt(4)" ::: "memory");
  BARF();

  for (int T = 0; T < NT; ++T){
    const char* ldsS = ldsraw + ((T & 1) << 16);
    s16x8 af[4], bf[4];
    rdA(ldsS, 0, 0, af); rdB(ldsS, 0, bf);
    if (T + 1 < NT) stageA(T + 1, 1);
    BARF();
    __builtin_amdgcn_s_setprio(1);
    #pragma unroll
    for (int mf = 0; mf < 4; ++mf)
      #pragma unroll
      for (int nf = 0; nf < 4; ++nf)
        acc[mf][nf] = __builtin_amdgcn_mfma_f32_16x16x32_bf16(af[mf], bf[nf], acc[mf][nf], 0, 0, 0);
    __builtin_amdgcn_s_setprio(0);
    BARF();
    rdA(ldsS, 1, 0, af);
    if (T + 1 < NT) stageB(T + 1, 1);
    BARF();
    __builtin_amdgcn_s_setprio(1);
    #pragma unroll
    for (int mf = 0; mf < 4; ++mf)
      #pragma unroll
      for (int nf = 0; nf < 4; ++nf)
        acc[4 + mf][nf] = __builtin_amdgcn_mfma_f32_16x16x32_bf16(af[mf], bf[nf], acc[4 + mf][nf], 0, 0, 0);
    __builtin_amdgcn_s_setprio(0);
    BARF();
    rdA(ldsS, 0, 1, af); rdB(ldsS, 1, bf);
    if (T + 2 < NT) stageB(T + 2, 0);
    BARF();
    __builtin_amdgcn_s_setprio(1);
    #pragma unroll
    for (int mf = 0; mf < 4; ++mf)
      #pragma unroll
      for (int nf = 0; nf < 4; ++nf)
        acc[mf][nf] = __builtin_amdgcn_mfma_f32_16x16x32_bf16(af[mf], bf[nf], acc[mf][nf], 0, 0, 0);
    __builtin_amdgcn_s_setprio(0);
    BARF();
    rdA(ldsS, 1, 1, af);
    if (T + 2 < NT) stageA(T + 2, 0);
    BARF();
    __builtin_amdgcn_s_setprio(1);
    #pragma unroll
    for (int mf = 0; mf < 4; ++mf)
      #pragma unroll
      for (int nf = 0; nf < 4; ++nf)
        acc[4 + mf][nf] = __builtin_amdgcn_mfma_f32_16x16x32_bf16(af[mf], bf[nf], acc[4 + mf][nf], 0, 0, 0);
    __builtin_amdgcn_s_setprio(0);
    if (T < NT - 2) { asm volatile("s_waitcnt vmcnt(4)" ::: "memory"); }
    else           { asm volatile("s_waitcnt vmcnt(0)" ::: "memory"); }
    BARF();
  }

  const int er0 = bm + wm*128 + ((lane >> 4) << 2);
  const int ec0 = bn + wn*64  + (lane & 15);

  if (EPI == 7){
    // ---- direct attention-update epilogue: o = Cf + v/lsum[row] ----
    #pragma unroll
    for (int mf = 0; mf < 8; ++mf){
      #pragma unroll
      for (int j = 0; j < 4; ++j){
        const int row = er0 + mf*16 + j;
        const float li = 1.0f / lsum[row];
        #pragma unroll
        for (int nf = 0; nf < 4; ++nf){
          const int col = ec0 + nf*16;
          const size_t idx = (size_t)row * N + col;
          const float o = Cf[idx] + li * acc[mf][nf][j];
          Cf[idx] = o;
          Cb[idx] = f2b(o);
        }
      }
    }
  } else {
    // ---- exp-store + fused row sums (LDS atomic -> 1 global atomic/row) ----
    float* lds_rs = (float*)ldsraw;      // staging LDS is dead past the final barrier
    if (tid < 256) lds_rs[tid] = 0.f;
    __syncthreads();

    #pragma unroll
    for (int mf = 0; mf < 8; ++mf){
      float rs[4] = {0.f, 0.f, 0.f, 0.f};
      #pragma unroll
      for (int nf = 0; nf < 4; ++nf){
        #pragma unroll
        for (int j = 0; j < 4; ++j){
          const int row = er0 + mf*16 + j;
          const int col = ec0 + nf*16;
          const size_t idx = (size_t)row * N + col;
          const float v = acc[mf][nf][j];
          unsigned short eb;
          if (EPI == 5){ eb = f2b(__expf(v * scale)); }
          else { const float zz = v * scale; Cf[idx] = zz; eb = f2b(__expf(zz)); }
          Cb[idx] = eb;
          rs[j] += b2f(eb);
        }
      }
      #pragma unroll
      for (int o = 8; o; o >>= 1){
        #pragma unroll
        for (int j = 0; j < 4; ++j) rs[j] += __shfl_xor(rs[j], o, 64);
      }
      if ((lane & 15) == 0){
        const int rbase = wm*128 + mf*16 + ((lane >> 4) << 2);
        #pragma unroll
        for (int j = 0; j < 4; ++j) atomicAdd(&lds_rs[rbase + j], rs[j]);
      }
    }
    __syncthreads();
    if (tid < 256) atomicAdd(&lsum[bm + tid], lds_rs[tid]);
  }
}

// ============================================================================
// 128x128 2-phase GEMM for projections and split-K partials
// EPI 2: Cb = bf16(v + bias[row])
// EPI 4: Cf[bz*M*N + idx] = v
// ============================================================================
template<int EPI>
__global__ __launch_bounds__(256, 4) void gemm_bt(
    const unsigned short* __restrict__ A, const unsigned short* __restrict__ B,
    int M, int N, int KS, float scale, const float* __restrict__ bias,
    float* __restrict__ Cf, unsigned short* __restrict__ Cb)
{
  __shared__ unsigned short As[128*64];
  __shared__ unsigned short Bs[128*64];
  const int tid  = threadIdx.x;
  const int wid  = tid >> 6, lane = tid & 63;
  const int wr   = wid >> 1, wc = wid & 1;

  const unsigned gx = gridDim.x, gy = gridDim.y;
  const unsigned lin = blockIdx.x + gx*(blockIdx.y + gy*blockIdx.z);
  const unsigned w   = xcd_swizzle(lin, gx*gy*gridDim.z);
  const unsigned bxs = w % gx;
  const unsigned rest = w / gx;
  const unsigned bys = rest % gy;
  const unsigned bzs = rest / gy;

  const int bm   = bys * 128, bn = bxs * 128;
  const int kb   = bzs * KS, ke = kb + KS;

  f32x4 acc[4][4] = {};

  const int l8   = lane >> 3;
  const int scol = ((((lane & 7) << 4) ^ (l8 << 4)) >> 1);
  const int Klead = gridDim.z * KS;

  const unsigned short* Ag[4]; const unsigned short* Bg[4];
  unsigned short* Al[4]; unsigned short* Bl[4];
  #pragma unroll
  for (int i = 0; i < 4; ++i){
    const int row = wid*32 + i*8 + l8;
    Ag[i] = A + (size_t)(bm + row) * Klead + scol;
    Bg[i] = B + (size_t)(bn + row) * Klead + scol;
    Al[i] = As + (wid*4 + i) * 512;
    Bl[i] = Bs + (wid*4 + i) * 512;
  }

  const int fr    = lane & 15;
  const int fk    = (lane >> 4) << 4;
  const int amask = (fr & 7) << 4;

  for (int k0 = kb; k0 < ke; k0 += 64){
    if (k0 != kb) __syncthreads();
    #pragma unroll
    for (int i = 0; i < 4; ++i){
      gload_lds16(Ag[i] + k0, Al[i]);
      gload_lds16(Bg[i] + k0, Bl[i]);
    }
    __syncthreads();
    #pragma unroll
    for (int kk = 0; kk < 2; ++kk){
      s16x8 af[4], bf[4];
      #pragma unroll
      for (int m = 0; m < 4; ++m){
        const int row = (wr << 6) + m*16 + fr;
        const int off = row*128 + (((kk << 6) + fk) ^ amask);
        af[m] = *(const s16x8*)((const char*)As + off);
      }
      #pragma unroll
      for (int n = 0; n < 4; ++n){
        const int row = (wc << 6) + n*16 + fr;
        const int off = row*128 + (((kk << 6) + fk) ^ amask);
        bf[n] = *(const s16x8*)((const char*)Bs + off);
      }
      #pragma unroll
      for (int m = 0; m < 4; ++m)
        #pragma unroll
        for (int n = 0; n < 4; ++n)
          acc[m][n] = __builtin_amdgcn_mfma_f32_16x16x32_bf16(af[m], bf[n], acc[m][n], 0, 0, 0);
    }
  }

  const int gr0 = bm + (wr << 6) + ((lane >> 4) << 2);
  const int gc0 = bn + (wc << 6) + (lane & 15);
  const size_t pbase = (size_t)bzs * M * N;
  #pragma unroll
  for (int m = 0; m < 4; ++m){
    #pragma unroll
    for (int j = 0; j < 4; ++j){
      const int row = gr0 + m*16 + j;
      #pragma unroll
      for (int n = 0; n < 4; ++n){
        const int col = gc0 + n*16;
        const size_t idx = (size_t)row * N + col;
        const float v = acc[m][n][j];
        if      (EPI == 2) Cb[idx] = f2b(v + bias[row]);
        else if (EPI == 4) Cf[pbase + idx] = v;
      }
    }
  }
}

// split-K reduce with row normalization (reads lsum, divides inline)
__global__ __launch_bounds__(256) void reduce_splitk(
    const float* __restrict__ P, int S, size_t stride4,
    const float* __restrict__ lsum, int d4,
    float* __restrict__ Cf, unsigned short* __restrict__ Cb, int n4)
{
  const int i = blockIdx.x * 256 + threadIdx.x;
  if (i >= n4) return;
  f32x4 s = {0.f, 0.f, 0.f, 0.f};
  for (int k = 0; k < S; ++k) s += ((const f32x4*)P)[(size_t)k * stride4 + i];
  const float li = 1.0f / lsum[i / d4];
  f32x4 r = ((const f32x4*)Cf)[i];
  r += s * li;
  ((f32x4*)Cf)[i] = r;
  u16x4 o;
  o[0] = f2b(r[0]); o[1] = f2b(r[1]); o[2] = f2b(r[2]); o[3] = f2b(r[3]);
  ((u16x4*)Cb)[i] = o;
}

// fp32 -> (optional fp32 copy) + bf16
__global__ void cvt8(const float* __restrict__ src, float* __restrict__ dstf,
                     unsigned short* __restrict__ dstb, int n8)
{
  const int i = blockIdx.x * 256 + threadIdx.x;
  if (i >= n8) return;
  const f32x4 a = ((const f32x4*)src)[2*i];
  const f32x4 b = ((const f32x4*)src)[2*i + 1];
  if (dstf){ ((f32x4*)dstf)[2*i] = a; ((f32x4*)dstf)[2*i + 1] = b; }
  u16x8 o;
  o[0]=f2b(a[0]); o[1]=f2b(a[1]); o[2]=f2b(a[2]); o[3]=f2b(a[3]);
  o[4]=f2b(b[0]); o[5]=f2b(b[1]); o[6]=f2b(b[2]); o[7]=f2b(b[3]);
  ((u16x8*)dstb)[i] = o;
}

extern "C" void kernel_launch(void* const* d_in, const int* in_sizes, int n_in,
                              void* d_out, int out_size, void* d_ws, size_t ws_size,
                              hipStream_t stream)
{
  (void)in_sizes; (void)n_in; (void)out_size; (void)ws_size;
  const float* sents = (const float*)d_in[0];
  const float* funcs = (const float*)d_in[1];
  const float* WvA   = (const float*)d_in[2];   // Wv_f2s
  const float* bvA   = (const float*)d_in[3];
  const float* WvB   = (const float*)d_in[4];   // Wv_s2f
  const float* bvB   = (const float*)d_in[5];

  const int NS = 16384, NF = 4096, D = 768;

  float* outS = (float*)d_out;                        // [NS, D]
  float* outF = outS + (size_t)NS * D;                // [NF, D]
  float* outZ = outF + (size_t)NF * D;                // [NS, NF]

  char* ws = (char*)d_ws;
  unsigned short* att = (unsigned short*)ws;  ws += (size_t)NS * NF * 2;   // shared att / z2 buffer
  unsigned short* z2  = att;                                               // disjoint lifetimes
  unsigned short* sb  = (unsigned short*)ws;  ws += (size_t)NS * D * 2;
  unsigned short* fb  = (unsigned short*)ws;  ws += (size_t)NF * D * 2;
  unsigned short* fvT = (unsigned short*)ws;  ws += (size_t)D * NF * 2;
  unsigned short* svT = (unsigned short*)ws;  ws += (size_t)D * NS * 2;
  unsigned short* wA  = (unsigned short*)ws;  ws += (size_t)D * D * 2;
  unsigned short* wB  = (unsigned short*)ws;  ws += (size_t)D * D * 2;
  float* lsum = (float*)ws;  ws += (size_t)NS * 4;          // 64KB row sums (atomic)
  float* Pbuf = (float*)ws;  ws += (size_t)NF * D * 4 * 4;  // 50.3MB split-K partials (fupd S=4)

  const float scale = 0.036084391824351615f;  // 1/sqrt(768)

  cvt8<<<dim3((NS*D/8 + 255)/256), 256, 0, stream>>>(sents, outS, sb, NS*D/8);
  cvt8<<<dim3((NF*D/8 + 255)/256), 256, 0, stream>>>(funcs, outF, fb, NF*D/8);
  cvt8<<<dim3((D*D/8 + 255)/256),  256, 0, stream>>>(WvA, nullptr, wA, D*D/8);
  cvt8<<<dim3((D*D/8 + 255)/256),  256, 0, stream>>>(WvB, nullptr, wB, D*D/8);

  for (int it = 0; it < 4; ++it){
    // fvT[d][f] = Wv_f2s @ func_hid^T + bias  (= func_val^T)
    gemm_bt<2><<<dim3(NF/128, D/128, 1), dim3(256), 0, stream>>>(wA, fb, D, NF, D, 0.f, bvA, nullptr, fvT);
    // att = exp(scale * sents_hid @ func_hid^T) + fused row sums
    hipMemsetAsync(lsum, 0, NS*4, stream);
    if (it < 3){
      gemm256<5><<<dim3(NF/256, NS/256), dim3(512), 0, stream>>>(sb, fb, NS, NF, D, scale, nullptr, att, lsum);
    } else {
      gemm256<6><<<dim3(NF/256, NS/256), dim3(512), 0, stream>>>(sb, fb, NS, NF, D, scale, outZ, att, lsum);
    }
    // sents_hid += (att_un @ func_val) / lsum  — 8-phase engine, direct epilogue update
    gemm256<7><<<dim3(D/256, NS/256), dim3(512), 0, stream>>>(att, fvT, NS, D, NF, 0.f, outS, sb, lsum);
    // svT[d][s] = Wv_s2f @ sents_hid^T + bias  (= sent_val^T)
    gemm_bt<2><<<dim3(NS/128, D/128, 1), dim3(256), 0, stream>>>(wB, sb, D, NS, D, 0.f, bvB, nullptr, svT);
    // z2_un = exp(scale * func_hid @ sents_hid^T) + fused row sums
    hipMemsetAsync(lsum, 0, NF*4, stream);
    gemm256<5><<<dim3(NS/256, NF/256), dim3(512), 0, stream>>>(fb, sb, NF, NS, D, scale, nullptr, z2, lsum);
    // func_hid += (z2_un @ sent_val) / lsum : split-K S=4, then reduce (inline 1/lsum)
    gemm_bt<4><<<dim3(D/128, NF/128, 4), dim3(256), 0, stream>>>(z2, svT, NF, D, 4096, 0.f, nullptr, Pbuf, nullptr);
    reduce_splitk<<<dim3(NF*D/4/256), 256, 0, stream>>>(Pbuf, 4, (size_t)NF*D/4, lsum, D/4, outF, fb, NF*D/4);
  }
}

// Round 12
// 2190.278 us; speedup vs baseline: 1.0262x; 1.0262x over previous
//
#include <hip/hip_runtime.h>
#include <stdint.h>

typedef __attribute__((ext_vector_type(8))) short s16x8;
typedef __attribute__((ext_vector_type(8))) unsigned short u16x8;
typedef __attribute__((ext_vector_type(4))) unsigned short u16x4;
typedef __attribute__((ext_vector_type(4))) float f32x4;

__device__ inline unsigned short f2b(float f){
  unsigned u = __builtin_bit_cast(unsigned, f);
  u = u + 0x7fffu + ((u >> 16) & 1u);
  return (unsigned short)(u >> 16);
}
__device__ inline float b2f(unsigned short h){
  unsigned u = ((unsigned)h) << 16;
  return __builtin_bit_cast(float, u);
}

typedef __attribute__((address_space(1))) const unsigned g_uint;
typedef __attribute__((address_space(3))) unsigned l_uint;

__device__ inline void gload_lds16(const void* g, void* l){
  __builtin_amdgcn_global_load_lds((g_uint*)reinterpret_cast<uintptr_t>(g),
                                   (l_uint*)reinterpret_cast<uintptr_t>(l), 16, 0, 0);
}

#define BARF() { __builtin_amdgcn_s_barrier(); asm volatile("" ::: "memory"); }

// plain bijective XCD swizzle (total % 8 == 0) — round-8 proven form
__device__ inline unsigned xcd_swizzle(unsigned lin, unsigned tot){
  const unsigned q = tot >> 3;
  return (lin & 7) * q + (lin >> 3);
}

// ============================================================================
// 256x256 8-phase GEMM (T2+T3+T4+T5), C = A·B^T, K multiple of 128.
// EPI 5: Cb = bf16(exp(v*scale)) + fused row-sum atomics into lsum
// EPI 6: EPI5 + Cf = v*scale
// ============================================================================
template<int EPI>
__global__ __launch_bounds__(512, 2) void gemm256(
    const unsigned short* __restrict__ A, const unsigned short* __restrict__ B,
    int M, int N, int K, float scale,
    float* __restrict__ Cf, unsigned short* __restrict__ Cb,
    float* __restrict__ lsum)
{
  __shared__ __align__(16) char ldsraw[131072];
  const int tid  = threadIdx.x;
  const int wid  = tid >> 6, lane = tid & 63;
  const int wm   = wid >> 2, wn = wid & 3;

  const unsigned gx = gridDim.x, gy = gridDim.y;
  const unsigned lin = blockIdx.x + gx*blockIdx.y;
  const unsigned w   = xcd_swizzle(lin, gx*gy);
  const int bm = (w / gx) * 256, bn = (w % gx) * 256;

  const int NT = K >> 6;

  f32x4 acc[8][4] = {};

  auto stageA = [&](int T, int halfm){
    const int kb = T << 6;
    char* ldsb = ldsraw + ((T & 1) << 16) + halfm*16384;
    #pragma unroll
    for (int i = 0; i < 2; ++i){
      const int lr  = i*64 + (tid >> 3);
      const int gtr = halfm*64 + ((lr < 64) ? lr : lr + 64);
      const int sc  = ((tid & 7)*8) ^ ((lr & 7)*8);
      gload_lds16(A + (size_t)(bm + gtr)*K + kb + sc, ldsb + i*8192 + tid*16);
    }
  };
  auto stageB = [&](int T, int halfk){
    const int kb = (T << 6) + halfk*32;
    char* ldsb = ldsraw + ((T & 1) << 16) + 32768 + halfk*16384;
    #pragma unroll
    for (int i = 0; i < 2; ++i){
      const int lr = i*128 + (tid >> 2);
      const int sc = ((tid & 3)*8) ^ ((lr & 3)*8);
      gload_lds16(B + (size_t)(bn + lr)*K + kb + sc, ldsb + i*8192 + tid*16);
    }
  };

  const int fr = lane & 15;
  const int fo = (lane >> 4) << 4;
  const int amask = (fr & 7) << 4;
  const int bmask = (fr & 3) << 4;

  auto rdA = [&](const char* ldsS, int mh, int kk, s16x8* af){
    const char* ab = ldsS + mh*16384;
    #pragma unroll
    for (int mf = 0; mf < 4; ++mf){
      const int r = wm*64 + mf*16 + fr;
      af[mf] = *(const s16x8*)(ab + r*128 + ((kk*64 + fo) ^ amask));
    }
  };
  auto rdB = [&](const char* ldsS, int kk, s16x8* bf){
    const char* bb = ldsS + 32768 + kk*16384;
    #pragma unroll
    for (int nf = 0; nf < 4; ++nf){
      const int r = wn*64 + nf*16 + fr;
      bf[nf] = *(const s16x8*)(bb + r*64 + (fo ^ bmask));
    }
  };

  stageB(0, 0); stageA(0, 0); stageA(0, 1); stageB(0, 1);
  stageB(1, 0); stageA(1, 0);
  asm volatile("s_waitcnt vmcnt(4)" ::: "memory");
  BARF();

  for (int T = 0; T < NT; ++T){
    const char* ldsS = ldsraw + ((T & 1) << 16);
    s16x8 af[4], bf[4];
    rdA(ldsS, 0, 0, af); rdB(ldsS, 0, bf);
    if (T + 1 < NT) stageA(T + 1, 1);
    BARF();
    __builtin_amdgcn_s_setprio(1);
    #pragma unroll
    for (int mf = 0; mf < 4; ++mf)
      #pragma unroll
      for (int nf = 0; nf < 4; ++nf)
        acc[mf][nf] = __builtin_amdgcn_mfma_f32_16x16x32_bf16(af[mf], bf[nf], acc[mf][nf], 0, 0, 0);
    __builtin_amdgcn_s_setprio(0);
    BARF();
    rdA(ldsS, 1, 0, af);
    if (T + 1 < NT) stageB(T + 1, 1);
    BARF();
    __builtin_amdgcn_s_setprio(1);
    #pragma unroll
    for (int mf = 0; mf < 4; ++mf)
      #pragma unroll
      for (int nf = 0; nf < 4; ++nf)
        acc[4 + mf][nf] = __builtin_amdgcn_mfma_f32_16x16x32_bf16(af[mf], bf[nf], acc[4 + mf][nf], 0, 0, 0);
    __builtin_amdgcn_s_setprio(0);
    BARF();
    rdA(ldsS, 0, 1, af); rdB(ldsS, 1, bf);
    if (T + 2 < NT) stageB(T + 2, 0);
    BARF();
    __builtin_amdgcn_s_setprio(1);
    #pragma unroll
    for (int mf = 0; mf < 4; ++mf)
      #pragma unroll
      for (int nf = 0; nf < 4; ++nf)
        acc[mf][nf] = __builtin_amdgcn_mfma_f32_16x16x32_bf16(af[mf], bf[nf], acc[mf][nf], 0, 0, 0);
    __builtin_amdgcn_s_setprio(0);
    BARF();
    rdA(ldsS, 1, 1, af);
    if (T + 2 < NT) stageA(T + 2, 0);
    BARF();
    __builtin_amdgcn_s_setprio(1);
    #pragma unroll
    for (int mf = 0; mf < 4; ++mf)
      #pragma unroll
      for (int nf = 0; nf < 4; ++nf)
        acc[4 + mf][nf] = __builtin_amdgcn_mfma_f32_16x16x32_bf16(af[mf], bf[nf], acc[4 + mf][nf], 0, 0, 0);
    __builtin_amdgcn_s_setprio(0);
    if (T < NT - 2) { asm volatile("s_waitcnt vmcnt(4)" ::: "memory"); }
    else           { asm volatile("s_waitcnt vmcnt(0)" ::: "memory"); }
    BARF();
  }

  // ---- epilogue: exp-store + fused row sums (LDS atomic -> 1 global atomic/row) ----
  float* lds_rs = (float*)ldsraw;      // staging LDS is dead past the final barrier
  if (tid < 256) lds_rs[tid] = 0.f;
  __syncthreads();

  const int er0 = bm + wm*128 + ((lane >> 4) << 2);
  const int ec0 = bn + wn*64  + (lane & 15);
  #pragma unroll
  for (int mf = 0; mf < 8; ++mf){
    float rs[4] = {0.f, 0.f, 0.f, 0.f};
    #pragma unroll
    for (int nf = 0; nf < 4; ++nf){
      #pragma unroll
      for (int j = 0; j < 4; ++j){
        const int row = er0 + mf*16 + j;
        const int col = ec0 + nf*16;
        const size_t idx = (size_t)row * N + col;
        const float v = acc[mf][nf][j];
        unsigned short eb;
        if (EPI == 5){ eb = f2b(__expf(v * scale)); }
        else { const float zz = v * scale; Cf[idx] = zz; eb = f2b(__expf(zz)); }
        Cb[idx] = eb;
        rs[j] += b2f(eb);
      }
    }
    #pragma unroll
    for (int o = 8; o; o >>= 1){
      #pragma unroll
      for (int j = 0; j < 4; ++j) rs[j] += __shfl_xor(rs[j], o, 64);
    }
    if ((lane & 15) == 0){
      const int rbase = wm*128 + mf*16 + ((lane >> 4) << 2);
      #pragma unroll
      for (int j = 0; j < 4; ++j) atomicAdd(&lds_rs[rbase + j], rs[j]);
    }
  }
  __syncthreads();
  if (tid < 256) atomicAdd(&lsum[bm + tid], lds_rs[tid]);
}

// ============================================================================
// 128x128 2-phase GEMM for projections, split-K partials, and direct updates
// EPI 2: Cb = bf16(v + bias[row])
// EPI 4: Cf[bz*M*N + idx] = v
// EPI 7: o = Cf[idx] + v/lsum[row]; Cf = o; Cb = bf16(o)
// ============================================================================
template<int EPI>
__global__ __launch_bounds__(256, 4) void gemm_bt(
    const unsigned short* __restrict__ A, const unsigned short* __restrict__ B,
    int M, int N, int KS, float scale, const float* __restrict__ bias,
    const float* __restrict__ lsum,
    float* __restrict__ Cf, unsigned short* __restrict__ Cb)
{
  __shared__ unsigned short As[128*64];
  __shared__ unsigned short Bs[128*64];
  const int tid  = threadIdx.x;
  const int wid  = tid >> 6, lane = tid & 63;
  const int wr   = wid >> 1, wc = wid & 1;

  const unsigned gx = gridDim.x, gy = gridDim.y;
  const unsigned lin = blockIdx.x + gx*(blockIdx.y + gy*blockIdx.z);
  const unsigned w   = xcd_swizzle(lin, gx*gy*gridDim.z);
  const unsigned bxs = w % gx;
  const unsigned rest = w / gx;
  const unsigned bys = rest % gy;
  const unsigned bzs = rest / gy;

  const int bm   = bys * 128, bn = bxs * 128;
  const int kb   = bzs * KS, ke = kb + KS;

  f32x4 acc[4][4] = {};

  const int l8   = lane >> 3;
  const int scol = ((((lane & 7) << 4) ^ (l8 << 4)) >> 1);
  const int Klead = gridDim.z * KS;

  const unsigned short* Ag[4]; const unsigned short* Bg[4];
  unsigned short* Al[4]; unsigned short* Bl[4];
  #pragma unroll
  for (int i = 0; i < 4; ++i){
    const int row = wid*32 + i*8 + l8;
    Ag[i] = A + (size_t)(bm + row) * Klead + scol;
    Bg[i] = B + (size_t)(bn + row) * Klead + scol;
    Al[i] = As + (wid*4 + i) * 512;
    Bl[i] = Bs + (wid*4 + i) * 512;
  }

  const int fr    = lane & 15;
  const int fk    = (lane >> 4) << 4;
  const int amask = (fr & 7) << 4;

  for (int k0 = kb; k0 < ke; k0 += 64){
    if (k0 != kb) __syncthreads();
    #pragma unroll
    for (int i = 0; i < 4; ++i){
      gload_lds16(Ag[i] + k0, Al[i]);
      gload_lds16(Bg[i] + k0, Bl[i]);
    }
    __syncthreads();
    #pragma unroll
    for (int kk = 0; kk < 2; ++kk){
      s16x8 af[4], bf[4];
      #pragma unroll
      for (int m = 0; m < 4; ++m){
        const int row = (wr << 6) + m*16 + fr;
        const int off = row*128 + (((kk << 6) + fk) ^ amask);
        af[m] = *(const s16x8*)((const char*)As + off);
      }
      #pragma unroll
      for (int n = 0; n < 4; ++n){
        const int row = (wc << 6) + n*16 + fr;
        const int off = row*128 + (((kk << 6) + fk) ^ amask);
        bf[n] = *(const s16x8*)((const char*)Bs + off);
      }
      #pragma unroll
      for (int m = 0; m < 4; ++m)
        #pragma unroll
        for (int n = 0; n < 4; ++n)
          acc[m][n] = __builtin_amdgcn_mfma_f32_16x16x32_bf16(af[m], bf[n], acc[m][n], 0, 0, 0);
    }
  }

  const int gr0 = bm + (wr << 6) + ((lane >> 4) << 2);
  const int gc0 = bn + (wc << 6) + (lane & 15);
  const size_t pbase = (size_t)bzs * M * N;
  #pragma unroll
  for (int m = 0; m < 4; ++m){
    #pragma unroll
    for (int j = 0; j < 4; ++j){
      const int row = gr0 + m*16 + j;
      const float li = (EPI == 7) ? 1.0f / lsum[row] : 0.f;
      #pragma unroll
      for (int n = 0; n < 4; ++n){
        const int col = gc0 + n*16;
        const size_t idx = (size_t)row * N + col;
        const float v = acc[m][n][j];
        if      (EPI == 2) Cb[idx] = f2b(v + bias[row]);
        else if (EPI == 4) Cf[pbase + idx] = v;
        else if (EPI == 7){ const float o = Cf[idx] + li * v; Cf[idx] = o; Cb[idx] = f2b(o); }
      }
    }
  }
}

// split-K reduce with row normalization (reads lsum, divides inline)
__global__ __launch_bounds__(256) void reduce_splitk(
    const float* __restrict__ P, int S, size_t stride4,
    const float* __restrict__ lsum, int d4,
    float* __restrict__ Cf, unsigned short* __restrict__ Cb, int n4)
{
  const int i = blockIdx.x * 256 + threadIdx.x;
  if (i >= n4) return;
  f32x4 s = {0.f, 0.f, 0.f, 0.f};
  for (int k = 0; k < S; ++k) s += ((const f32x4*)P)[(size_t)k * stride4 + i];
  const float li = 1.0f / lsum[i / d4];
  f32x4 r = ((const f32x4*)Cf)[i];
  r += s * li;
  ((f32x4*)Cf)[i] = r;
  u16x4 o;
  o[0] = f2b(r[0]); o[1] = f2b(r[1]); o[2] = f2b(r[2]); o[3] = f2b(r[3]);
  ((u16x4*)Cb)[i] = o;
}

// fp32 -> (optional fp32 copy) + bf16
__global__ void cvt8(const float* __restrict__ src, float* __restrict__ dstf,
                     unsigned short* __restrict__ dstb, int n8)
{
  const int i = blockIdx.x * 256 + threadIdx.x;
  if (i >= n8) return;
  const f32x4 a = ((const f32x4*)src)[2*i];
  const f32x4 b = ((const f32x4*)src)[2*i + 1];
  if (dstf){ ((f32x4*)dstf)[2*i] = a; ((f32x4*)dstf)[2*i + 1] = b; }
  u16x8 o;
  o[0]=f2b(a[0]); o[1]=f2b(a[1]); o[2]=f2b(a[2]); o[3]=f2b(a[3]);
  o[4]=f2b(b[0]); o[5]=f2b(b[1]); o[6]=f2b(b[2]); o[7]=f2b(b[3]);
  ((u16x8*)dstb)[i] = o;
}

extern "C" void kernel_launch(void* const* d_in, const int* in_sizes, int n_in,
                              void* d_out, int out_size, void* d_ws, size_t ws_size,
                              hipStream_t stream)
{
  (void)in_sizes; (void)n_in; (void)out_size; (void)ws_size;
  const float* sents = (const float*)d_in[0];
  const float* funcs = (const float*)d_in[1];
  const float* WvA   = (const float*)d_in[2];   // Wv_f2s
  const float* bvA   = (const float*)d_in[3];
  const float* WvB   = (const float*)d_in[4];   // Wv_s2f
  const float* bvB   = (const float*)d_in[5];

  const int NS = 16384, NF = 4096, D = 768;

  float* outS = (float*)d_out;                        // [NS, D]
  float* outF = outS + (size_t)NS * D;                // [NF, D]
  float* outZ = outF + (size_t)NF * D;                // [NS, NF]

  char* ws = (char*)d_ws;
  unsigned short* att = (unsigned short*)ws;  ws += (size_t)NS * NF * 2;   // shared att / z2 buffer
  unsigned short* z2  = att;                                               // disjoint lifetimes
  unsigned short* sb  = (unsigned short*)ws;  ws += (size_t)NS * D * 2;
  unsigned short* fb  = (unsigned short*)ws;  ws += (size_t)NF * D * 2;
  unsigned short* fvT = (unsigned short*)ws;  ws += (size_t)D * NF * 2;
  unsigned short* svT = (unsigned short*)ws;  ws += (size_t)D * NS * 2;
  unsigned short* wA  = (unsigned short*)ws;  ws += (size_t)D * D * 2;
  unsigned short* wB  = (unsigned short*)ws;  ws += (size_t)D * D * 2;
  float* lsum = (float*)ws;  ws += (size_t)NS * 4;          // 64KB row sums (atomic)
  float* Pbuf = (float*)ws;  ws += (size_t)NF * D * 4 * 4;  // 50.3MB split-K partials (fupd S=4)

  const float scale = 0.036084391824351615f;  // 1/sqrt(768)

  cvt8<<<dim3((NS*D/8 + 255)/256), 256, 0, stream>>>(sents, outS, sb, NS*D/8);
  cvt8<<<dim3((NF*D/8 + 255)/256), 256, 0, stream>>>(funcs, outF, fb, NF*D/8);
  cvt8<<<dim3((D*D/8 + 255)/256),  256, 0, stream>>>(WvA, nullptr, wA, D*D/8);
  cvt8<<<dim3((D*D/8 + 255)/256),  256, 0, stream>>>(WvB, nullptr, wB, D*D/8);

  for (int it = 0; it < 4; ++it){
    // fvT[d][f] = Wv_f2s @ func_hid^T + bias  (= func_val^T)
    gemm_bt<2><<<dim3(NF/128, D/128, 1), dim3(256), 0, stream>>>(wA, fb, D, NF, D, 0.f, bvA, nullptr, nullptr, fvT);
    // att = exp(scale * sents_hid @ func_hid^T) + fused row sums
    hipMemsetAsync(lsum, 0, NS*4, stream);
    if (it < 3){
      gemm256<5><<<dim3(NF/256, NS/256), dim3(512), 0, stream>>>(sb, fb, NS, NF, D, scale, nullptr, att, lsum);
    } else {
      gemm256<6><<<dim3(NF/256, NS/256), dim3(512), 0, stream>>>(sb, fb, NS, NF, D, scale, outZ, att, lsum);
    }
    // sents_hid += (att_un @ func_val) / lsum  — direct epilogue update, 4 blocks/CU
    gemm_bt<7><<<dim3(D/128, NS/128, 1), dim3(256), 0, stream>>>(att, fvT, NS, D, NF, 0.f, nullptr, lsum, outS, sb);
    // svT[d][s] = Wv_s2f @ sents_hid^T + bias  (= sent_val^T)
    gemm_bt<2><<<dim3(NS/128, D/128, 1), dim3(256), 0, stream>>>(wB, sb, D, NS, D, 0.f, bvB, nullptr, nullptr, svT);
    // z2_un = exp(scale * func_hid @ sents_hid^T) + fused row sums
    hipMemsetAsync(lsum, 0, NF*4, stream);
    gemm256<5><<<dim3(NS/256, NF/256), dim3(512), 0, stream>>>(fb, sb, NF, NS, D, scale, nullptr, z2, lsum);
    // func_hid += (z2_un @ sent_val) / lsum : split-K S=4, then reduce (inline 1/lsum)
    gemm_bt<4><<<dim3(D/128, NF/128, 4), dim3(256), 0, stream>>>(z2, svT, NF, D, 4096, 0.f, nullptr, nullptr, Pbuf, nullptr);
    reduce_splitk<<<dim3(NF*D/4/256), 256, 0, stream>>>(Pbuf, 4, (size_t)NF*D/4, lsum, D/4, outF, fb, NF*D/4);
  }
}